// Round 4
// baseline (1715.936 us; speedup 1.0000x reference)
//
#include <hip/hip_runtime.h>
#include <stdint.h>

typedef unsigned short u16;
typedef __attribute__((ext_vector_type(8))) short short8;
typedef __attribute__((ext_vector_type(4))) float f32x4;

#define VOCAB 50257
#define KHOT  1024

__device__ __forceinline__ float bf2f(u16 u) {
  union { uint32_t i; float f; } c; c.i = ((uint32_t)u) << 16; return c.f;
}
__device__ __forceinline__ u16 f2bf(float f) {
  union { float f; uint32_t i; } c; c.f = f;
  uint32_t r = (c.i + 0x7FFFu + ((c.i >> 16) & 1u)) >> 16;
  return (u16)r;
}
// flag-aware float load: f32 flag set -> read float, else widen bf16
__device__ __forceinline__ float ldf(const void* p, size_t i, int f32) {
  return f32 ? ((const float*)p)[i] : bf2f(((const u16*)p)[i]);
}

// async global->LDS, 16B per lane. LDS dest must be wave-uniform base; HW adds lane*16.
#define GLOAD16(gp, lp)                                                        \
  __builtin_amdgcn_global_load_lds(                                            \
      (const __attribute__((address_space(1))) void*)(gp),                     \
      (__attribute__((address_space(3))) void*)(lp), 16, 0, 0)

// ---- detect input float dtype from freqs[0]==1.0 exactly ----
// f32: word0 = 0x3F800000 (low16 == 0). bf16 pair: low16 = 0x3F80 != 0.
__global__ void detect_kernel(const void* __restrict__ freqs, int* __restrict__ flags) {
  uint32_t w = *(const uint32_t*)freqs;
  flags[0] = ((w & 0xFFFFu) == 0u) ? 1 : 0;
}

__global__ void normalize_bf16(const void* __restrict__ src, u16* __restrict__ dst,
                               int n, const int* __restrict__ flags) {
  int f32 = flags[0];
  int i = blockIdx.x * 256 + threadIdx.x;
  if (i < n) dst[i] = f2bf(ldf(src, i, f32));
}

// ---------------- phi: Fourier features, padded to 128 cols ----------------
__global__ void phi_kernel(const int* __restrict__ tok, int c0,
                           const void* __restrict__ freqs, u16* __restrict__ PHI,
                           const int* __restrict__ flags) {
  int f32 = flags[0];
  int row = blockIdx.x;
  int t = threadIdx.x;               // 128 threads
  int id = tok ? tok[row] : (c0 + row);
  float x = (float)id / (float)VOCAB;
  float v = 0.0f;
  if (t < 48)       v = sinf(x * ldf(freqs, t, f32));
  else if (t < 96)  v = cosf(x * ldf(freqs, t - 48, f32));
  else if (t < 104) v = (float)((id >> (2 * (t - 96))) & 3) * (1.0f / 3.0f);
  PHI[(size_t)row * 128 + t] = f2bf(v);
}

// ---------------- transpose K x N -> N x Kpad bf16 (zero-padded) ----------------
__global__ void transpose_pad(const void* __restrict__ src, u16* __restrict__ dst,
                              int Ksrc, int N, int Kpad, const int* __restrict__ flags) {
  int f32 = flags[0];
  __shared__ u16 tile[32][33];
  int kb = blockIdx.x * 32, nb = blockIdx.y * 32;
  int tx = threadIdx.x & 31, ty = threadIdx.x >> 5;   // 256 thr = 32x8
  for (int i = ty; i < 32; i += 8) {
    int k = kb + i, n = nb + tx;
    u16 v = 0;
    if (k < Ksrc && n < N) v = f2bf(ldf(src, (size_t)k * N + n, f32));
    tile[i][tx] = v;
  }
  __syncthreads();
  for (int i = ty; i < 32; i += 8) {
    int n = nb + i, k = kb + tx;
    if (n < N && k < Kpad) dst[(size_t)n * Kpad + k] = tile[tx][i];
  }
}

// ---------------- overwrite hot rows of E with (U@B)[old_to_new[v]] ----------------
__global__ void overwrite_hot(u16* __restrict__ E, const int* __restrict__ tok, int c0,
                              const int* __restrict__ o2n, const u16* __restrict__ Hot) {
  int row = blockIdx.x;
  int id;
  if (tok) id = tok[row];
  else { id = c0 + row; if (id >= VOCAB) return; }
  int k = o2n[id];
  if (k < KHOT) {
    int t = threadIdx.x;  // 128 threads x 8 u16 = 1024 cols
    *(uint4*)(E + (size_t)row * 1024 + t * 8) =
        *(const uint4*)(Hot + (size_t)k * 1024 + t * 8);
  }
}

// ---------------- generic bf16 MFMA GEMM: C[m,n] = op(sum_k A[m,k]*Bt[n,k]) -------
// A: M x K row-major bf16, Bt: N x K row-major bf16. M,N mult of 128, K mult of 64.
// op 0: C = s*(acc+bias) ; op 1: C = gelu_exact(acc+bias) ; op 2: C = s*acc + bias
// scale_mode: 0 none, 1 direct scalar, 2 exp(scalar)
// C element index = m*ldc + col_off + n (n GLOBAL across grid.y); n masked by n_limit.
// store f32 iff (c_is_out && flags[0])
// Staging: global_load_lds width=16, LINEAR LDS (gload_lds needs contiguous dest),
// DOUBLE-BUFFERED with ONE barrier per K-step (T3 minimum 2-phase): stage tile t+1
// is issued before compute of tile t; the compiler-emitted vmcnt(0) drain before
// s_barrier lands AFTER compute, so load latency hides under MFMA+ds_read.
// Hazards: at each barrier, (a) vmcnt drained -> buf[cur] staged; (b) all waves
// consumed their ds_reads of buf[cur^1] -> next stage may overwrite it.
// Block swizzle: bijective XCD-chunked remap (m204).
#define BM 128
#define BN 128
#define BK 64
__global__ __launch_bounds__(256) void gemm_bt(
    const u16* __restrict__ A, const u16* __restrict__ Bt, void* __restrict__ C,
    int M, int N, int K, int ldc, int col_off, int n_limit,
    const void* __restrict__ bias,
    const void* __restrict__ scale_ptr, int scale_mode, int op,
    const int* __restrict__ flags, int c_is_out) {
  __shared__ __attribute__((aligned(16))) u16 As[2][BM * BK];
  __shared__ __attribute__((aligned(16))) u16 Bs[2][BN * BK];
  const int tid  = threadIdx.x;
  const int lane = tid & 63;
  const int wave = tid >> 6;
  const int wr = wave >> 1, wc = wave & 1;

  // bijective XCD-chunked swizzle (m204)
  const int gx = gridDim.x;
  const int nwg = gx * gridDim.y;
  const int orig = blockIdx.y * gx + blockIdx.x;
  const int xcd = orig & 7, local = orig >> 3;
  const int q = nwg >> 3, r = nwg & 7;
  const int w = (xcd < r ? xcd * (q + 1) : r * (q + 1) + (xcd - r) * q) + local;
  const int m0 = (w % gx) * BM;
  const int n0 = (w / gx) * BN;
  const int f32 = flags[0];

  f32x4 acc[4][4];
#pragma unroll
  for (int i = 0; i < 4; ++i)
#pragma unroll
    for (int j = 0; j < 4; ++j) acc[i][j] = (f32x4){0.f, 0.f, 0.f, 0.f};

  // staging coords: q = p*256 + tid covers 1024 16B-chunks per matrix.
  const int srow = tid >> 3, skb = tid & 7;
  const size_t sgoff = (size_t)srow * K + skb * 8;
  const int wbase = tid & 192;                            // wave * 64

  const int nsteps = K / BK;

  // prologue: stage tile 0 into buffer 0
#pragma unroll
  for (int p = 0; p < 4; ++p) {
    GLOAD16(A  + (size_t)(m0 + p * 32) * K + sgoff, &As[0][(p * 256 + wbase) * 8]);
    GLOAD16(Bt + (size_t)(n0 + p * 32) * K + sgoff, &Bs[0][(p * 256 + wbase) * 8]);
  }

  for (int s = 0; s < nsteps; ++s) {
    const int cur = s & 1;
    __syncthreads();   // compiler drains vmcnt+lgkmcnt: buf[cur] staged, buf[cur^1] free
    if (s + 1 < nsteps) {
      const size_t kt = (size_t)(s + 1) * BK;
#pragma unroll
      for (int p = 0; p < 4; ++p) {
        GLOAD16(A  + (size_t)(m0 + p * 32) * K + kt + sgoff, &As[cur ^ 1][(p * 256 + wbase) * 8]);
        GLOAD16(Bt + (size_t)(n0 + p * 32) * K + kt + sgoff, &Bs[cur ^ 1][(p * 256 + wbase) * 8]);
      }
    }
#pragma unroll
    for (int ks = 0; ks < 2; ++ks) {
      short8 af[4], bfr[4];
#pragma unroll
      for (int t = 0; t < 4; ++t) {
        int m  = wr * 64 + t * 16 + (lane & 15);
        int kb = ks * 4 + (lane >> 4);              // k-block 0..7
        af[t]  = *(const short8*)(&As[cur][m * BK + kb * 8]);
        int n  = wc * 64 + t * 16 + (lane & 15);
        bfr[t] = *(const short8*)(&Bs[cur][n * BK + kb * 8]);
      }
#pragma unroll
      for (int i = 0; i < 4; ++i)
#pragma unroll
        for (int j = 0; j < 4; ++j)
          acc[i][j] = __builtin_amdgcn_mfma_f32_16x16x32_bf16(af[i], bfr[j], acc[i][j], 0, 0, 0);
    }
  }

  float s = 1.0f;
  if (scale_ptr) {
    float sv = ldf(scale_ptr, 0, f32);
    s = (scale_mode == 2) ? expf(sv) : sv;
  }
  const int store_f32 = c_is_out && f32;
#pragma unroll
  for (int i = 0; i < 4; ++i) {
#pragma unroll
    for (int j = 0; j < 4; ++j) {
      int n = n0 + wc * 64 + j * 16 + (lane & 15);   // GLOBAL column within this GEMM
      if (n < n_limit) {
        float bv = bias ? ldf(bias, (size_t)col_off + n, f32) : 0.0f;
#pragma unroll
        for (int r2 = 0; r2 < 4; ++r2) {
          int m = m0 + wr * 64 + i * 16 + ((lane >> 4) << 2) + r2;
          float v = acc[i][j][r2];
          float outv;
          if (op == 0)      outv = s * (v + bv);
          else if (op == 1) { float x = v + bv; outv = 0.5f * x * (1.0f + erff(x * 0.70710678118654752f)); }
          else              outv = s * v + bv;
          size_t cidx = (size_t)m * ldc + col_off + n;
          if (store_f32) ((float*)C)[cidx] = outv;
          else           ((u16*)C)[cidx]   = f2bf(outv);
        }
      }
    }
  }
}

static inline size_t alignup(size_t x) { return (x + 255) & ~(size_t)255; }

extern "C" void kernel_launch(void* const* d_in, const int* in_sizes, int n_in,
                              void* d_out, int out_size, void* d_ws, size_t ws_size,
                              hipStream_t stream) {
  const int* tokens     = (const int*)d_in[0];
  const int* o2n        = (const int*)d_in[1];
  // d_in[2] = new_to_old: algebraically absorbed (inverse of o2n)
  const void* freqs     = d_in[3];
  const void* U         = d_in[4];
  const void* Bm        = d_in[5];
  const void* W1        = d_in[6];
  const void* b1        = d_in[7];
  const void* W2        = d_in[8];
  const void* b2        = d_in[9];
  const void* W3        = d_in[10];
  const void* b3        = d_in[11];
  const void* tail_gain = d_in[12];
  const void* log_alpha = d_in[13];
  const void* out_bias  = d_in[14];
  const int T = in_sizes[0];  // 2048 tokens

  char* ws = (char*)d_ws;
  size_t off = 0;
  auto take = [&](size_t bytes) { char* p = ws + off; off += alignup(bytes); return p; };
  int* flags = (int*)take(256);
  u16* W1t = (u16*)take((size_t)1024 * 128 * 2);
  u16* W2t = (u16*)take((size_t)1024 * 1024 * 2);
  u16* W3t = (u16*)take((size_t)1024 * 1024 * 2);
  u16* Btr = (u16*)take((size_t)1024 * 768 * 2);
  u16* Un  = (u16*)take((size_t)1024 * 768 * 2);
  u16* Hot = (u16*)take((size_t)1024 * 1024 * 2);
  u16* Lat = (u16*)take((size_t)T * 1024 * 2);
  size_t fixed = off;
  // per-row chunk bytes: PHI 256 + H1 2048 + H2 2048 = 4352.
  // Largest chunk that fits (multiple of 128, capped at whole padded vocab).
  int chunk = 2048;
  {
    size_t avail = (ws_size > fixed + 4096) ? (ws_size - fixed - 4096) : 0;
    long maxrows = (long)(avail / 4352);
    long c = (maxrows / 128) * 128;
    if (c > 50432) c = 50432;
    if (c < 2048)  c = 2048;
    if (c < T)     c = T;        // latent path reuses H1/H2 for T rows
    chunk = (int)c;
  }
  u16* PHI = (u16*)take((size_t)chunk * 128 * 2);
  u16* H1  = (u16*)take((size_t)chunk * 1024 * 2);
  u16* H2  = (u16*)take((size_t)chunk * 1024 * 2);

  detect_kernel<<<1, 1, 0, stream>>>(freqs, flags);

  // weight transposes (N x Kpad bf16 layouts for gemm_bt)
  transpose_pad<<<dim3(4, 32),  256, 0, stream>>>(W1, W1t, 104, 1024, 128, flags);
  transpose_pad<<<dim3(32, 32), 256, 0, stream>>>(W2, W2t, 1024, 1024, 1024, flags);
  transpose_pad<<<dim3(32, 32), 256, 0, stream>>>(W3, W3t, 1024, 1024, 1024, flags);
  transpose_pad<<<dim3(24, 32), 256, 0, stream>>>(Bm, Btr, 768, 1024, 768, flags);
  normalize_bf16<<<(1024 * 768 + 255) / 256, 256, 0, stream>>>(U, Un, 1024 * 768, flags);

  // Hot = U @ B  (M=1024, N=1024, K=768)
  gemm_bt<<<dim3(8, 8), 256, 0, stream>>>(Un, Btr, Hot, 1024, 1024, 768, 1024, 0, 1024,
                                          nullptr, nullptr, 0, 0, flags, 0);

  // ---- latent rows for the 2048 tokens ----
  phi_kernel<<<T, 128, 0, stream>>>(tokens, 0, freqs, PHI, flags);
  gemm_bt<<<dim3(T / 128, 8), 256, 0, stream>>>(PHI, W1t, H2, T, 1024, 128, 1024, 0, 1024,
                                                b1, nullptr, 0, 1, flags, 0);
  gemm_bt<<<dim3(T / 128, 8), 256, 0, stream>>>(H2, W2t, H1, T, 1024, 1024, 1024, 0, 1024,
                                                b2, nullptr, 0, 1, flags, 0);
  gemm_bt<<<dim3(T / 128, 8), 256, 0, stream>>>(H1, W3t, Lat, T, 1024, 1024, 1024, 0, 1024,
                                                b3, tail_gain, 1, 0, flags, 0);
  overwrite_hot<<<T, 128, 0, stream>>>(Lat, tokens, 0, o2n, Hot);

  // ---- E rows chunk-by-chunk, fused into logits GEMM ----
  for (int c0 = 0; c0 < VOCAB; c0 += chunk) {
    int rows = VOCAB - c0;
    int Mc = rows >= chunk ? chunk : ((rows + 127) / 128) * 128;
    phi_kernel<<<Mc, 128, 0, stream>>>(nullptr, c0, freqs, PHI, flags);
    gemm_bt<<<dim3(Mc / 128, 8), 256, 0, stream>>>(PHI, W1t, H2, Mc, 1024, 128, 1024, 0, 1024,
                                                   b1, nullptr, 0, 1, flags, 0);
    gemm_bt<<<dim3(Mc / 128, 8), 256, 0, stream>>>(H2, W2t, H1, Mc, 1024, 1024, 1024, 0, 1024,
                                                   b2, nullptr, 0, 1, flags, 0);
    gemm_bt<<<dim3(Mc / 128, 8), 256, 0, stream>>>(H1, W3t, H2, Mc, 1024, 1024, 1024, 0, 1024,
                                                   b3, tail_gain, 1, 0, flags, 0);
    u16* Echunk = H2;  // final E rows live in H2 this iteration
    overwrite_hot<<<Mc, 128, 0, stream>>>(Echunk, nullptr, c0, o2n, Hot);
    int nlim = rows < Mc ? rows : Mc;
    // out[:, c0:c0+nlim] = exp(log_alpha) * Lat @ Echunk^T + out_bias[c0:...]
    gemm_bt<<<dim3(T / 128, Mc / 128), 256, 0, stream>>>(Lat, Echunk, d_out, T, Mc, 1024,
                                                         VOCAB, c0, nlim, out_bias,
                                                         log_alpha, 2, 2, flags, 1);
  }
  (void)n_in; (void)out_size; (void)in_sizes;
}

// Round 5
// 1613.339 us; speedup vs baseline: 1.0636x; 1.0636x over previous
//
#include <hip/hip_runtime.h>
#include <stdint.h>

typedef unsigned short u16;
typedef __attribute__((ext_vector_type(8))) short short8;
typedef __attribute__((ext_vector_type(4))) float f32x4;

#define VOCAB 50257
#define KHOT  1024

__device__ __forceinline__ float bf2f(u16 u) {
  union { uint32_t i; float f; } c; c.i = ((uint32_t)u) << 16; return c.f;
}
__device__ __forceinline__ u16 f2bf(float f) {
  union { float f; uint32_t i; } c; c.f = f;
  uint32_t r = (c.i + 0x7FFFu + ((c.i >> 16) & 1u)) >> 16;
  return (u16)r;
}
// flag-aware float load: f32 flag set -> read float, else widen bf16
__device__ __forceinline__ float ldf(const void* p, size_t i, int f32) {
  return f32 ? ((const float*)p)[i] : bf2f(((const u16*)p)[i]);
}

// async global->LDS, 16B per lane. LDS dest must be wave-uniform base; HW adds lane*16.
#define GLOAD16(gp, lp)                                                        \
  __builtin_amdgcn_global_load_lds(                                            \
      (const __attribute__((address_space(1))) void*)(gp),                     \
      (__attribute__((address_space(3))) void*)(lp), 16, 0, 0)

// ---- detect input float dtype from freqs[0]==1.0 exactly ----
// f32: word0 = 0x3F800000 (low16 == 0). bf16 pair: low16 = 0x3F80 != 0.
__global__ void detect_kernel(const void* __restrict__ freqs, int* __restrict__ flags) {
  uint32_t w = *(const uint32_t*)freqs;
  flags[0] = ((w & 0xFFFFu) == 0u) ? 1 : 0;
}

__global__ void normalize_bf16(const void* __restrict__ src, u16* __restrict__ dst,
                               int n, const int* __restrict__ flags) {
  int f32 = flags[0];
  int i = blockIdx.x * 256 + threadIdx.x;
  if (i < n) dst[i] = f2bf(ldf(src, i, f32));
}

// ---------------- phi: Fourier features, padded to 128 cols ----------------
__global__ void phi_kernel(const int* __restrict__ tok, int c0,
                           const void* __restrict__ freqs, u16* __restrict__ PHI,
                           const int* __restrict__ flags) {
  int f32 = flags[0];
  int row = blockIdx.x;
  int t = threadIdx.x;               // 128 threads
  int id = tok ? tok[row] : (c0 + row);
  float x = (float)id / (float)VOCAB;
  float v = 0.0f;
  if (t < 48)       v = sinf(x * ldf(freqs, t, f32));
  else if (t < 96)  v = cosf(x * ldf(freqs, t - 48, f32));
  else if (t < 104) v = (float)((id >> (2 * (t - 96))) & 3) * (1.0f / 3.0f);
  PHI[(size_t)row * 128 + t] = f2bf(v);
}

// ---------------- transpose K x N -> N x Kpad bf16 (zero-padded) ----------------
__global__ void transpose_pad(const void* __restrict__ src, u16* __restrict__ dst,
                              int Ksrc, int N, int Kpad, const int* __restrict__ flags) {
  int f32 = flags[0];
  __shared__ u16 tile[32][33];
  int kb = blockIdx.x * 32, nb = blockIdx.y * 32;
  int tx = threadIdx.x & 31, ty = threadIdx.x >> 5;   // 256 thr = 32x8
  for (int i = ty; i < 32; i += 8) {
    int k = kb + i, n = nb + tx;
    u16 v = 0;
    if (k < Ksrc && n < N) v = f2bf(ldf(src, (size_t)k * N + n, f32));
    tile[i][tx] = v;
  }
  __syncthreads();
  for (int i = ty; i < 32; i += 8) {
    int n = nb + i, k = kb + tx;
    if (n < N && k < Kpad) dst[(size_t)n * Kpad + k] = tile[tx][i];
  }
}

// ---------------- overwrite hot rows of E with (U@B)[old_to_new[v]] ----------------
__global__ void overwrite_hot(u16* __restrict__ E, const int* __restrict__ tok, int c0,
                              const int* __restrict__ o2n, const u16* __restrict__ Hot) {
  int row = blockIdx.x;
  int id;
  if (tok) id = tok[row];
  else { id = c0 + row; if (id >= VOCAB) return; }
  int k = o2n[id];
  if (k < KHOT) {
    int t = threadIdx.x;  // 128 threads x 8 u16 = 1024 cols
    *(uint4*)(E + (size_t)row * 1024 + t * 8) =
        *(const uint4*)(Hot + (size_t)k * 1024 + t * 8);
  }
}

// ---------------- generic bf16 MFMA GEMM: C[m,n] = op(sum_k A[m,k]*Bt[n,k]) -------
// A: M x K row-major bf16, Bt: N x K row-major bf16. M,N mult of 128, K mult of 64.
// op 0: C = s*(acc+bias) ; op 1: C = gelu_exact(acc+bias) ; op 2: C = s*acc + bias
// scale_mode: 0 none, 1 direct scalar, 2 exp(scalar)
// C element index = m*ldc + col_off + n (n GLOBAL across grid.y); n masked by n_limit.
// store f32 iff (c_is_out && flags[0])
// Staging: global_load_lds width=16 into LINEAR LDS dest, double-buffered, one
// barrier per K-step. BANK-CONFLICT FIX (rule #21 both-sides-or-neither): logical
// (row, kb16) lives at LDS chunk row*8 + (kb16 ^ (row&7)). gload_lds dest stays
// linear; each lane's GLOBAL source is inverse-swizzled (involution), and fragment
// reads apply the same XOR. Without this, row-stride-128B reads are a 16-way
// conflict (lanes 0-15 same bank quad): measured 7.7e7 conflict cycles/dispatch.
// Block swizzle: bijective XCD-chunked remap (m204).
#define BM 128
#define BN 128
#define BK 64
__global__ __launch_bounds__(256) void gemm_bt(
    const u16* __restrict__ A, const u16* __restrict__ Bt, void* __restrict__ C,
    int M, int N, int K, int ldc, int col_off, int n_limit,
    const void* __restrict__ bias,
    const void* __restrict__ scale_ptr, int scale_mode, int op,
    const int* __restrict__ flags, int c_is_out) {
  __shared__ __attribute__((aligned(16))) u16 As[2][BM * BK];
  __shared__ __attribute__((aligned(16))) u16 Bs[2][BN * BK];
  const int tid  = threadIdx.x;
  const int lane = tid & 63;
  const int wave = tid >> 6;
  const int wr = wave >> 1, wc = wave & 1;

  // bijective XCD-chunked swizzle (m204)
  const int gx = gridDim.x;
  const int nwg = gx * gridDim.y;
  const int orig = blockIdx.y * gx + blockIdx.x;
  const int xcd = orig & 7, local = orig >> 3;
  const int q = nwg >> 3, r = nwg & 7;
  const int w = (xcd < r ? xcd * (q + 1) : r * (q + 1) + (xcd - r) * q) + local;
  const int m0 = (w % gx) * BM;
  const int n0 = (w / gx) * BN;
  const int f32 = flags[0];

  f32x4 acc[4][4];
#pragma unroll
  for (int i = 0; i < 4; ++i)
#pragma unroll
    for (int j = 0; j < 4; ++j) acc[i][j] = (f32x4){0.f, 0.f, 0.f, 0.f};

  // staging coords: thread stages LDS chunk (p*256 + tid), 16B each.
  // linear chunk ci = p*256+tid -> row = ci>>3 = p*32 + (tid>>3); since p*32 % 8 == 0,
  // row&7 = (tid>>3)&7. Inverse-swizzled global kb16: (tid&7) ^ (row&7).
  const int srow = tid >> 3;
  const int skb  = (tid & 7) ^ (srow & 7);
  const size_t sgoff = (size_t)srow * K + skb * 8;
  const int wbase = tid & 192;                            // wave * 64

  const int nsteps = K / BK;

  // prologue: stage tile 0 into buffer 0
#pragma unroll
  for (int p = 0; p < 4; ++p) {
    GLOAD16(A  + (size_t)(m0 + p * 32) * K + sgoff, &As[0][(p * 256 + wbase) * 8]);
    GLOAD16(Bt + (size_t)(n0 + p * 32) * K + sgoff, &Bs[0][(p * 256 + wbase) * 8]);
  }

  for (int s = 0; s < nsteps; ++s) {
    const int cur = s & 1;
    __syncthreads();   // compiler drains vmcnt+lgkmcnt: buf[cur] staged, buf[cur^1] free
    if (s + 1 < nsteps) {
      const size_t kt = (size_t)(s + 1) * BK;
#pragma unroll
      for (int p = 0; p < 4; ++p) {
        GLOAD16(A  + (size_t)(m0 + p * 32) * K + kt + sgoff, &As[cur ^ 1][(p * 256 + wbase) * 8]);
        GLOAD16(Bt + (size_t)(n0 + p * 32) * K + kt + sgoff, &Bs[cur ^ 1][(p * 256 + wbase) * 8]);
      }
    }
#pragma unroll
    for (int ks = 0; ks < 2; ++ks) {
      short8 af[4], bfr[4];
#pragma unroll
      for (int t = 0; t < 4; ++t) {
        int m  = wr * 64 + t * 16 + (lane & 15);
        int kb = ks * 4 + (lane >> 4);              // logical k-block 0..7
        int sw = kb ^ (lane & 7);                   // m&7 == n&7 == lane&7
        af[t]  = *(const short8*)(&As[cur][m * BK + sw * 8]);
        int n  = wc * 64 + t * 16 + (lane & 15);
        bfr[t] = *(const short8*)(&Bs[cur][n * BK + sw * 8]);
      }
#pragma unroll
      for (int i = 0; i < 4; ++i)
#pragma unroll
        for (int j = 0; j < 4; ++j)
          acc[i][j] = __builtin_amdgcn_mfma_f32_16x16x32_bf16(af[i], bfr[j], acc[i][j], 0, 0, 0);
    }
  }

  float s = 1.0f;
  if (scale_ptr) {
    float sv = ldf(scale_ptr, 0, f32);
    s = (scale_mode == 2) ? expf(sv) : sv;
  }
  const int store_f32 = c_is_out && f32;
#pragma unroll
  for (int i = 0; i < 4; ++i) {
#pragma unroll
    for (int j = 0; j < 4; ++j) {
      int n = n0 + wc * 64 + j * 16 + (lane & 15);   // GLOBAL column within this GEMM
      if (n < n_limit) {
        float bv = bias ? ldf(bias, (size_t)col_off + n, f32) : 0.0f;
#pragma unroll
        for (int r2 = 0; r2 < 4; ++r2) {
          int m = m0 + wr * 64 + i * 16 + ((lane >> 4) << 2) + r2;
          float v = acc[i][j][r2];
          float outv;
          if (op == 0)      outv = s * (v + bv);
          else if (op == 1) { float x = v + bv; outv = 0.5f * x * (1.0f + erff(x * 0.70710678118654752f)); }
          else              outv = s * v + bv;
          size_t cidx = (size_t)m * ldc + col_off + n;
          if (store_f32) ((float*)C)[cidx] = outv;
          else           ((u16*)C)[cidx]   = f2bf(outv);
        }
      }
    }
  }
}

static inline size_t alignup(size_t x) { return (x + 255) & ~(size_t)255; }

extern "C" void kernel_launch(void* const* d_in, const int* in_sizes, int n_in,
                              void* d_out, int out_size, void* d_ws, size_t ws_size,
                              hipStream_t stream) {
  const int* tokens     = (const int*)d_in[0];
  const int* o2n        = (const int*)d_in[1];
  // d_in[2] = new_to_old: algebraically absorbed (inverse of o2n)
  const void* freqs     = d_in[3];
  const void* U         = d_in[4];
  const void* Bm        = d_in[5];
  const void* W1        = d_in[6];
  const void* b1        = d_in[7];
  const void* W2        = d_in[8];
  const void* b2        = d_in[9];
  const void* W3        = d_in[10];
  const void* b3        = d_in[11];
  const void* tail_gain = d_in[12];
  const void* log_alpha = d_in[13];
  const void* out_bias  = d_in[14];
  const int T = in_sizes[0];  // 2048 tokens

  char* ws = (char*)d_ws;
  size_t off = 0;
  auto take = [&](size_t bytes) { char* p = ws + off; off += alignup(bytes); return p; };
  int* flags = (int*)take(256);
  u16* W1t = (u16*)take((size_t)1024 * 128 * 2);
  u16* W2t = (u16*)take((size_t)1024 * 1024 * 2);
  u16* W3t = (u16*)take((size_t)1024 * 1024 * 2);
  u16* Btr = (u16*)take((size_t)1024 * 768 * 2);
  u16* Un  = (u16*)take((size_t)1024 * 768 * 2);
  u16* Hot = (u16*)take((size_t)1024 * 1024 * 2);
  u16* Lat = (u16*)take((size_t)T * 1024 * 2);
  size_t fixed = off;
  // per-row chunk bytes: PHI 256 + H1 2048 + H2 2048 = 4352.
  // Largest chunk that fits (multiple of 128, capped at whole padded vocab).
  int chunk = 2048;
  {
    size_t avail = (ws_size > fixed + 4096) ? (ws_size - fixed - 4096) : 0;
    long maxrows = (long)(avail / 4352);
    long c = (maxrows / 128) * 128;
    if (c > 50432) c = 50432;
    if (c < 2048)  c = 2048;
    if (c < T)     c = T;        // latent path reuses H1/H2 for T rows
    chunk = (int)c;
  }
  u16* PHI = (u16*)take((size_t)chunk * 128 * 2);
  u16* H1  = (u16*)take((size_t)chunk * 1024 * 2);
  u16* H2  = (u16*)take((size_t)chunk * 1024 * 2);

  detect_kernel<<<1, 1, 0, stream>>>(freqs, flags);

  // weight transposes (N x Kpad bf16 layouts for gemm_bt)
  transpose_pad<<<dim3(4, 32),  256, 0, stream>>>(W1, W1t, 104, 1024, 128, flags);
  transpose_pad<<<dim3(32, 32), 256, 0, stream>>>(W2, W2t, 1024, 1024, 1024, flags);
  transpose_pad<<<dim3(32, 32), 256, 0, stream>>>(W3, W3t, 1024, 1024, 1024, flags);
  transpose_pad<<<dim3(24, 32), 256, 0, stream>>>(Bm, Btr, 768, 1024, 768, flags);
  normalize_bf16<<<(1024 * 768 + 255) / 256, 256, 0, stream>>>(U, Un, 1024 * 768, flags);

  // Hot = U @ B  (M=1024, N=1024, K=768)
  gemm_bt<<<dim3(8, 8), 256, 0, stream>>>(Un, Btr, Hot, 1024, 1024, 768, 1024, 0, 1024,
                                          nullptr, nullptr, 0, 0, flags, 0);

  // ---- latent rows for the 2048 tokens ----
  phi_kernel<<<T, 128, 0, stream>>>(tokens, 0, freqs, PHI, flags);
  gemm_bt<<<dim3(T / 128, 8), 256, 0, stream>>>(PHI, W1t, H2, T, 1024, 128, 1024, 0, 1024,
                                                b1, nullptr, 0, 1, flags, 0);
  gemm_bt<<<dim3(T / 128, 8), 256, 0, stream>>>(H2, W2t, H1, T, 1024, 1024, 1024, 0, 1024,
                                                b2, nullptr, 0, 1, flags, 0);
  gemm_bt<<<dim3(T / 128, 8), 256, 0, stream>>>(H1, W3t, Lat, T, 1024, 1024, 1024, 0, 1024,
                                                b3, tail_gain, 1, 0, flags, 0);
  overwrite_hot<<<T, 128, 0, stream>>>(Lat, tokens, 0, o2n, Hot);

  // ---- E rows chunk-by-chunk, fused into logits GEMM ----
  for (int c0 = 0; c0 < VOCAB; c0 += chunk) {
    int rows = VOCAB - c0;
    int Mc = rows >= chunk ? chunk : ((rows + 127) / 128) * 128;
    phi_kernel<<<Mc, 128, 0, stream>>>(nullptr, c0, freqs, PHI, flags);
    gemm_bt<<<dim3(Mc / 128, 8), 256, 0, stream>>>(PHI, W1t, H2, Mc, 1024, 128, 1024, 0, 1024,
                                                   b1, nullptr, 0, 1, flags, 0);
    gemm_bt<<<dim3(Mc / 128, 8), 256, 0, stream>>>(H2, W2t, H1, Mc, 1024, 1024, 1024, 0, 1024,
                                                   b2, nullptr, 0, 1, flags, 0);
    gemm_bt<<<dim3(Mc / 128, 8), 256, 0, stream>>>(H1, W3t, H2, Mc, 1024, 1024, 1024, 0, 1024,
                                                   b3, tail_gain, 1, 0, flags, 0);
    u16* Echunk = H2;  // final E rows live in H2 this iteration
    overwrite_hot<<<Mc, 128, 0, stream>>>(Echunk, nullptr, c0, o2n, Hot);
    int nlim = rows < Mc ? rows : Mc;
    // out[:, c0:c0+nlim] = exp(log_alpha) * Lat @ Echunk^T + out_bias[c0:...]
    gemm_bt<<<dim3(T / 128, Mc / 128), 256, 0, stream>>>(Lat, Echunk, d_out, T, Mc, 1024,
                                                         VOCAB, c0, nlim, out_bias,
                                                         log_alpha, 2, 2, flags, 1);
  }
  (void)n_in; (void)out_size; (void)in_sizes;
}